// Round 1
// baseline (130.307 us; speedup 1.0000x reference)
//
#include <hip/hip_runtime.h>

#define N_P   512
#define N_DIMC 3
#define N_K   32
#define N_T   10
#define BATCHC 8
#define EPSC  1e-6f

// ws layout (floats): [0..31] w_eff[k], [32..63] ig2[k], [64] const_term

__global__ void prep_kernel(const float* __restrict__ t,
                            const float* __restrict__ mus_time,
                            const float* __restrict__ nlg_time,
                            const float* __restrict__ weights,
                            const float* __restrict__ bias,
                            const float* __restrict__ importance,
                            const float* __restrict__ nlg,
                            float* __restrict__ ws) {
    __shared__ float trbf[N_T];
    __shared__ float w_eff_s[N_K];
    int k = threadIdx.x;
    if (k == 0) {
        float t0 = t[0];
        float r[N_T];
        float s = 0.f;
        for (int tt = 0; tt < N_T; ++tt) {
            float g = __expf(nlg_time[tt]);
            float diff = t0 - mus_time[tt];
            r[tt] = __expf(-diff * diff * g * g);
            s += r[tt];
        }
        float inv = 1.f / (EPSC + s);
        for (int tt = 0; tt < N_T; ++tt) trbf[tt] = r[tt] * inv;
    }
    __syncthreads();
    if (k < N_K) {
        float w = 0.f;
        for (int tt = 0; tt < N_T; ++tt) w = fmaf(weights[k * N_T + tt], trbf[tt], w);
        ws[k] = w;
        w_eff_s[k] = w;
        float g = __expf(nlg[k]);
        ws[N_K + k] = g * g;
    }
    __syncthreads();
    if (k == 0) {
        float c = 0.f;
        for (int tt = 0; tt < N_T; ++tt) c = fmaf(bias[tt], trbf[tt], c);
        for (int kk = 0; kk < N_K; ++kk) {
            float im = importance[kk];
            c = fmaf(im * im, w_eff_s[kk], c);
        }
        ws[2 * N_K] = c;
    }
}

__global__ __launch_bounds__(256) void
pair_kernel(const float* __restrict__ x,
            const float* __restrict__ mus,
            const float* __restrict__ ws,
            float* __restrict__ out) {
    const int b = blockIdx.x >> 9;         // blockIdx.x / N_P
    const int i = blockIdx.x & (N_P - 1);  // blockIdx.x % N_P

    __shared__ float sx[N_P], sy[N_P], sz[N_P];
    __shared__ float redx[4], redy[4], redz[4], redd[4];

    // stage x[b] into LDS as SoA
    const float* xb = x + b * (N_P * N_DIMC);
    for (int idx = threadIdx.x; idx < N_P * N_DIMC; idx += 256) {
        float v = xb[idx];
        int p = idx / 3;
        int c = idx - 3 * p;
        if (c == 0) sx[p] = v;
        else if (c == 1) sy[p] = v;
        else sz[p] = v;
    }

    // per-k constants: uniform loads -> scalar regs
    float muk[N_K], ig2[N_K], wk[N_K];
#pragma unroll
    for (int k = 0; k < N_K; ++k) {
        muk[k] = mus[k];
        ig2[k] = ws[N_K + k];
        wk[k]  = ws[k];
    }
    const float cterm = ws[2 * N_K];

    __syncthreads();

    const float xi_x = sx[i], xi_y = sy[i], xi_z = sz[i];

    float fx = 0.f, fy = 0.f, fz = 0.f, dv = 0.f;

#pragma unroll
    for (int j0 = 0; j0 < N_P; j0 += 256) {
        int j = j0 + threadIdx.x;
        if (j != i) {
            float dx = xi_x - sx[j];
            float dy = xi_y - sy[j];
            float dz = xi_z - sz[j];
            float d2 = fmaf(dx, dx, fmaf(dy, dy, dz * dz)) + EPSC;
            float d = sqrtf(d2);

            float rsum = 0.f, we = 0.f, ds = 0.f, wds = 0.f;
#pragma unroll
            for (int k = 0; k < N_K; ++k) {
                float diff = d - muk[k];
                float tt = diff * ig2[k];
                float e = __expf(-diff * tt);
                float te = tt * e;
                rsum += e;
                we = fmaf(wk[k], e, we);
                ds += te;
                wds = fmaf(wk[k], te, wds);
            }
            float inv = __builtin_amdgcn_rcpf(EPSC + rsum);
            float fmag = fmaf(we, inv, cterm);
            // dfm = -2*inv*(wds - we*ds*inv)
            float dfm = -2.f * inv * fmaf(-we * inv, ds, wds);

            fx = fmaf(dx, fmag, fx);
            fy = fmaf(dy, fmag, fy);
            fz = fmaf(dz, fmag, fz);
            dv += fmaf(d, dfm, 3.f * fmag);
        }
    }

    // block reduction: wave shuffle then LDS
#pragma unroll
    for (int off = 32; off >= 1; off >>= 1) {
        fx += __shfl_down(fx, off, 64);
        fy += __shfl_down(fy, off, 64);
        fz += __shfl_down(fz, off, 64);
        dv += __shfl_down(dv, off, 64);
    }
    int wave = threadIdx.x >> 6;
    int lane = threadIdx.x & 63;
    if (lane == 0) { redx[wave] = fx; redy[wave] = fy; redz[wave] = fz; redd[wave] = dv; }
    __syncthreads();
    if (threadIdx.x == 0) {
        float tfx = redx[0] + redx[1] + redx[2] + redx[3];
        float tfy = redy[0] + redy[1] + redy[2] + redy[3];
        float tfz = redz[0] + redz[1] + redz[2] + redz[3];
        float tdv = redd[0] + redd[1] + redd[2] + redd[3];
        float* outf = out + (b * N_P + i) * 3;
        outf[0] = tfx;
        outf[1] = tfy;
        outf[2] = tfz;
        atomicAdd(out + BATCHC * N_P * 3 + b, -tdv);
    }
}

extern "C" void kernel_launch(void* const* d_in, const int* in_sizes, int n_in,
                              void* d_out, int out_size, void* d_ws, size_t ws_size,
                              hipStream_t stream) {
    const float* t          = (const float*)d_in[0];
    const float* x          = (const float*)d_in[1];
    const float* mus        = (const float*)d_in[2];
    const float* nlg        = (const float*)d_in[3];
    const float* mus_time   = (const float*)d_in[4];
    const float* nlg_time   = (const float*)d_in[5];
    const float* weights    = (const float*)d_in[6];
    const float* bias       = (const float*)d_in[7];
    const float* importance = (const float*)d_in[8];
    float* out = (float*)d_out;
    float* ws  = (float*)d_ws;

    prep_kernel<<<1, 64, 0, stream>>>(t, mus_time, nlg_time, weights, bias,
                                      importance, nlg, ws);
    // zero the divergence slots (poisoned 0xAA before every timed launch)
    hipMemsetAsync(out + BATCHC * N_P * N_DIMC, 0, BATCHC * sizeof(float), stream);
    pair_kernel<<<BATCHC * N_P, 256, 0, stream>>>(x, mus, ws, out);
}